// Round 2
// 70.758 us; speedup vs baseline: 1.0278x; 1.0278x over previous
//
#include <hip/hip_runtime.h>
#include <math.h>

// 2D Gaussian splatting, tile-based with order-preserving culling.
// v2 (resubmit — previous bench was an infra failure, no counters produced):
//   - 64x8 tiles, 512 blocks x 256 threads, 2 px/thread
//     -> 2048 waves = 2 waves/SIMD (was 1: zero latency hiding), 2 blocks/CU.
//   - records are compacted DIRECTLY (register -> sg[pos*12]); the j-loop
//     reads sg[j*12] with affine addressing: one LDS hop instead of the
//     list[j] -> sg[idx*16] dependent chain, and the compiler can pipeline.
//   - record is 12 floats (bbox kept in registers only), stride 12 floats
//     also spreads LDS write banks (gcd(12,32)=4 -> 8-way address spread).
// Phases per 256-gaussian chunk (N=256 -> 1 chunk):
//   1 prep: thread i computes gaussian i's conic (exp2-folded), color, bbox
//           in REGISTERS; bbox-vs-tile predicate.
//   2 cull: ballot + wave-prefix -> surviving thread writes its record to
//           the compacted slot (order preserved; skipped alpha < e^-15,
//           worst-case output error <= N * 3.1e-7 ~ 8e-5).
//   3 composite: front-to-back over the ~5-30 survivors, 2 rows/thread.

#define BLOCK 256
#define QMAX 30.0f          // skip where q > 30  (alpha < e^-15)
#define ALPHA_CLIP 0.999f
#define LOG2E 1.4426950408889634f
#define RSTRIDE 12          // floats per compacted record

__global__ __launch_bounds__(BLOCK) void render_kernel(
    const float* __restrict__ xyz,
    const float* __restrict__ rot,
    const float* __restrict__ scal,
    const float* __restrict__ feat,
    const float* __restrict__ opac,
    const float* __restrict__ bg,
    const int* __restrict__ dH,
    const int* __restrict__ dW,
    float* __restrict__ out,
    int N, int P)
{
    __shared__ float sg[BLOCK * RSTRIDE];   // 12 KB compacted records
    __shared__ int   wcnt[BLOCK / 64];
    __shared__ int   sM;

    const int t = threadIdx.x;
    const int W = *dW, H = *dH;
    const int tiles_x = W >> 6;                  // 64-wide, 8-tall tiles
    const int tx0 = (blockIdx.x % tiles_x) << 6;
    const int ty0 = (blockIdx.x / tiles_x) << 3;

    const float fx0 = (float)tx0, fx1 = (float)(tx0 + 64);
    const float fy0 = (float)ty0, fy1 = (float)(ty0 + 8);

    const float gxp  = fx0 + (float)(t & 63) + 0.5f;   // this thread's pixel x
    const float gyp0 = fy0 + (float)(t >> 6) + 0.5f;   // row 0 of 2 (stride 4)

    float T[2]  = {1.f, 1.f};
    float ar[2] = {0.f, 0.f};
    float ag[2] = {0.f, 0.f};
    float ab[2] = {0.f, 0.f};

    for (int c0 = 0; c0 < N; c0 += BLOCK) {
        const int i = c0 + t;
        bool pred = false;
        float mx = 0.f, my = 0.f, ia2 = 0.f, ib2 = 0.f, ic2 = 0.f;
        float lop = 0.f, cr = 0.f, cg = 0.f, cb = 0.f;
        if (i < N) {
            // ---- per-gaussian prep (matches reference math), registers only ----
            const float Wf = (float)W, Hf = (float)H;
            mx = (xyz[2*i]   * 0.5f + 0.5f) * Wf;
            my = (xyz[2*i+1] * 0.5f + 0.5f) * Hf;
            const float r  = rot[i];
            const float theta = (1.0f / (1.0f + expf(-r))) * 6.283185307179586f;
            const float sd0 = 1.0f / (fabsf(scal[2*i])   + 1e-6f);
            const float sd1 = 1.0f / (fabsf(scal[2*i+1]) + 1e-6f);
            const float s0 = sd0 * sd0, s1 = sd1 * sd1;
            const float c = cosf(theta), s = sinf(theta);
            const float A  = c*c*s0 + s*s*s1;       // Sigma_xx
            const float B  = c*s*(s0 - s1);
            const float Cc = s*s*s0 + c*c*s1;       // Sigma_yy
            const float det = A*Cc - B*B + 1e-12f;
            const float inv = 1.0f / det;
            const float kk = -0.5f * LOG2E;
            const float rx = sqrtf(QMAX * A);       // max |dx| on q=QMAX ellipse
            const float ry = sqrtf(QMAX * Cc);

            ia2 = Cc * inv * kk;                    // ia' (exp2-folded)
            ib2 = -B * inv * 2.0f * kk;             // 2*ib'
            ic2 = A  * inv * kk;                    // ic'
            lop = log2f(opac[i]);                   // opacity folded into exponent
            cr  = feat[3*i+0];
            cg  = feat[3*i+1];
            cb  = feat[3*i+2];

            pred = (mx + rx >= fx0) & (mx - rx <= fx1) &
                   (my + ry >= fy0) & (my - ry <= fy1);
        }

        // ---- order-preserving compaction straight into LDS records ----
        const unsigned long long m = __ballot(pred);
        const int lane = t & 63, wid = t >> 6;
        if (lane == 0) wcnt[wid] = __popcll(m);
        __syncthreads();                        // wcnt visible; prev chunk done with sg
        int off = 0;
        for (int w = 0; w < wid; ++w) off += wcnt[w];
        if (pred) {
            const int pos = off + __popcll(m & ((1ull << lane) - 1ull));
            float* rec = &sg[pos * RSTRIDE];
            ((float4*)rec)[0] = make_float4(mx, my, ia2, ib2);
            ((float4*)rec)[1] = make_float4(ic2, lop, cr, cg);
            rec[8] = cb;
        }
        if (t == 0) sM = wcnt[0] + wcnt[1] + wcnt[2] + wcnt[3];
        __syncthreads();                        // records + sM visible
        const int M = sM;

        // ---- front-to-back composite over survivors (affine LDS addressing) ----
        for (int j = 0; j < M; ++j) {
            const float* rec = &sg[j * RSTRIDE];
            const float4 g0 = *(const float4*)rec;         // mx,my,ia',2ib'
            const float4 g1 = *(const float4*)(rec + 4);   // ic',lop,r,g
            const float  fb = rec[8];                      // b
            const float dx = gxp - g0.x;
            const float q0 = fmaf(g0.z * dx, dx, g1.y);    // ia'*dx^2 + lop
            const float bx = g0.w * dx;                    // 2ib'*dx
#pragma unroll
            for (int k = 0; k < 2; ++k) {
                const float dy = (gyp0 + 4.0f * (float)k) - g0.y;
                const float ea = fmaf(dy, fmaf(g1.x, dy, bx), q0);
                const float alpha = fminf(exp2f(ea), ALPHA_CLIP);
                const float w = alpha * T[k];
                ar[k] = fmaf(w, g1.z, ar[k]);
                ag[k] = fmaf(w, g1.w, ag[k]);
                ab[k] = fmaf(w, fb, ab[k]);
                T[k] -= w;                                 // T *= (1 - alpha)
            }
        }
        __syncthreads();                        // before next chunk reuses sg
    }

    // ---- background + store ----
    const float b0 = bg[0], b1 = bg[1], b2 = bg[2];
    const int px = tx0 + (t & 63);
#pragma unroll
    for (int k = 0; k < 2; ++k) {
        const int py = ty0 + (t >> 6) + 4 * k;
        if (px < W && py < H) {
            const int p = py * W + px;
            out[p]         = fmaf(b0, T[k], ar[k]);
            out[P + p]     = fmaf(b1, T[k], ag[k]);
            out[2*P + p]   = fmaf(b2, T[k], ab[k]);
        }
    }
}

extern "C" void kernel_launch(void* const* d_in, const int* in_sizes, int n_in,
                              void* d_out, int out_size, void* d_ws, size_t ws_size,
                              hipStream_t stream) {
    const float* xyz  = (const float*)d_in[0];
    const float* rot  = (const float*)d_in[1];
    const float* scal = (const float*)d_in[2];
    const float* feat = (const float*)d_in[3];
    const float* opac = (const float*)d_in[4];
    const float* bg   = (const float*)d_in[5];
    const int*   dH   = (const int*)d_in[6];
    const int*   dW   = (const int*)d_in[7];
    float* out = (float*)d_out;

    const int N = in_sizes[0] / 2;   // 256
    const int P = out_size / 3;      // H*W; tiles are 64x8 = 512 px

    const int blocks = (P + 511) / 512;   // H%8==0, W%64==0 for this problem
    render_kernel<<<blocks, BLOCK, 0, stream>>>(xyz, rot, scal, feat, opac, bg,
                                                dH, dW, out, N, P);
}